// Round 4
// baseline (37641.504 us; speedup 1.0000x reference)
//
#include <hip/hip_runtime.h>
#include <math.h>
#include <stdint.h>

#define NBATCH 512
#define SLEN   128
#define HDIM   256

// scratch layout in floats (static __device__ — independent of ws_size)
#define OFF_WHE  0            // Wh_enc packed [k][j][4]  262144
#define OFF_WHD  262144       // Wh_dec packed            262144
#define OFF_ME   524288       // M_enc  [k4][j][4]        4096
#define OFF_MD   528384       // M_dec                    4096
#define OFF_VE   532480       // v_enc  [j][4]            1024
#define OFF_VD   533504       // v_dec  [j][4]            1024
#define OFF_X0   534528       // x0 gates [j][4]          1024
#define OFF_WQG  535552       // WqgT [k][j]              65536
#define OFF_WQP  601088       // WqpT                     65536
#define OFF_WRGP 666624       // (Wr_g,Wr_p) [k][j][2]    131072
#define OFF_RG   797696       // refp_g [B][S][H]         16777216
#define OFF_RP   17574912     // refp_p                   16777216
#define WS_FLOATS 34352128    // ~137.4 MB

__device__ float g_ws[WS_FLOATS];

__device__ __forceinline__ float sigf(float x) { return 1.0f / (1.0f + expf(-x)); }

__device__ __forceinline__ void tf2x32(uint32_t k0, uint32_t k1, uint32_t x0, uint32_t x1,
                                       uint32_t& o0, uint32_t& o1) {
    uint32_t ks2 = k0 ^ k1 ^ 0x1BD11BDAu;
    x0 += k0; x1 += k1;
#define RR(r) { x0 += x1; x1 = (x1 << r) | (x1 >> (32 - r)); x1 ^= x0; }
    RR(13) RR(15) RR(26) RR(6)   x0 += k1;  x1 += ks2 + 1u;
    RR(17) RR(29) RR(16) RR(24)  x0 += ks2; x1 += k0 + 2u;
    RR(13) RR(15) RR(26) RR(6)   x0 += k0;  x1 += k1 + 3u;
    RR(17) RR(29) RR(16) RR(24)  x0 += k1;  x1 += ks2 + 4u;
    RR(13) RR(15) RR(26) RR(6)   x0 += ks2; x1 += k0 + 5u;
#undef RR
    o0 = x0; o1 = x1;
}

// JAX partitionable-threefry random_bits (bit_width=32), flat element n, key (k0,k1):
// bits[n] = xor(threefry2x32(key, (0, n)))  [verified: R3 actions exact]
__device__ __forceinline__ double gumbel_jax(uint32_t k0, uint32_t k1, uint32_t n) {
    uint32_t o0, o1; tf2x32(k0, k1, 0u, n, o0, o1);
    uint32_t bits = o0 ^ o1;
    float f = __uint_as_float((bits >> 9) | 0x3f800000u) - 1.0f;
    f = fmaxf(f, 1.17549435e-38f);
    return -log(-log((double)f));
}

__global__ void pre_k(const float* __restrict__ embed_W, const float* __restrict__ embed_b,
                      const float* __restrict__ Wi_enc, const float* __restrict__ Wh_enc,
                      const float* __restrict__ b_enc,
                      const float* __restrict__ Wi_dec, const float* __restrict__ Wh_dec,
                      const float* __restrict__ b_dec, const float* __restrict__ dec0,
                      const float* __restrict__ Wq_g, const float* __restrict__ Wr_g,
                      const float* __restrict__ Wq_p, const float* __restrict__ Wr_p) {
    float* ws = g_ws;
    int i0 = blockIdx.x * blockDim.x + threadIdx.x;
    int np = gridDim.x * blockDim.x;
    for (int i = i0; i < 262144; i += np) {
        int g = i & 3, j = (i >> 2) & 255, k = i >> 10, r = (g << 8) + j;
        ws[OFF_WHE + i] = Wh_enc[r * 256 + k];
        ws[OFF_WHD + i] = Wh_dec[r * 256 + k];
    }
    for (int i = i0; i < 65536; i += np) {
        int j = i & 255, k = i >> 8;
        ws[OFF_WQG + i] = Wq_g[j * 256 + k];
        ws[OFF_WQP + i] = Wq_p[j * 256 + k];
        ws[OFF_WRGP + 2 * i]     = Wr_g[j * 256 + k];
        ws[OFF_WRGP + 2 * i + 1] = Wr_p[j * 256 + k];
    }
    for (int i = i0; i < 4096; i += np) {
        int g = i & 3, j = (i >> 2) & 255, k4 = i >> 10, r = (g << 8) + j;
        const float* we = embed_W + k4 * 256;
        const float* wa = Wi_enc + r * 256;
        const float* wb = Wi_dec + r * 256;
        double a = 0.0, b = 0.0;
        for (int e = 0; e < 256; ++e) { a += (double)we[e] * wa[e]; b += (double)we[e] * wb[e]; }
        ws[OFF_ME + i] = (float)a; ws[OFF_MD + i] = (float)b;
    }
    for (int i = i0; i < 1024; i += np) {
        int g = i & 3, j = i >> 2, r = (g << 8) + j;
        const float* wa = Wi_enc + r * 256;
        const float* wb = Wi_dec + r * 256;
        double a = 0.0, b = 0.0, x = 0.0;
        for (int e = 0; e < 256; ++e) {
            a += (double)embed_b[e] * wa[e];
            b += (double)embed_b[e] * wb[e];
            x += (double)dec0[e] * wb[e];
        }
        ws[OFF_VE + i] = (float)(a + (double)b_enc[r]);
        ws[OFF_VD + i] = (float)(b + (double)b_dec[r]);
        ws[OFF_X0 + i] = (float)(x + (double)b_dec[r]);
    }
}

// One batch per block; 512 threads = (kh = tid>>8, j = tid&255) k-split matvecs.
__global__ __launch_bounds__(512) void main_k(
    const float* __restrict__ problems,
    const float* __restrict__ bq_g, const float* __restrict__ br_g, const float* __restrict__ V_g,
    const float* __restrict__ bq_p, const float* __restrict__ br_p, const float* __restrict__ V_p,
    float* __restrict__ out) {
    float* ws = g_ws;
    const int b = blockIdx.x;
    const int tid = threadIdx.x;
    const int kh = tid >> 8;
    const int j = tid & 255;
    const int lane = tid & 63, wave = tid >> 6;
    const int kbase = kh << 7;

    const float4* WhE = (const float4*)(ws + OFF_WHE);
    const float4* WhD = (const float4*)(ws + OFF_WHD);
    const float4* ME  = (const float4*)(ws + OFF_ME);
    const float4* MD  = (const float4*)(ws + OFF_MD);
    const float4* vE  = (const float4*)(ws + OFF_VE);
    const float4* vD  = (const float4*)(ws + OFF_VD);
    const float4* X0  = (const float4*)(ws + OFF_X0);
    const float*  WqgT = ws + OFF_WQG;
    const float*  WqpT = ws + OFF_WQP;
    const float2* Wrgp = (const float2*)(ws + OFF_WRGP);
    float* refg = ws + OFF_RG + (size_t)b * SLEN * HDIM;
    float* refp = ws + OFF_RP + (size_t)b * SLEN * HDIM;

    __shared__ double h_s[256];
    __shared__ double c_s[256];
    __shared__ double pG[2][256][4];   // gate / Wr partials
    __shared__ float  pA[2][256];      // qp_g partials
    __shared__ float  pQ[2][256];      // q partials
    __shared__ float  pP[2][256];      // qp_p partials
    __shared__ float  u_l[128];
    __shared__ float  w_l[128];
    __shared__ unsigned char vis[128];
    __shared__ int lastA;

    if (tid < 256) { h_s[tid] = 0.0; c_s[tid] = 0.0; }
    if (tid < 128) vis[tid] = 0;
    if (tid == 0) lastA = 0;
    __syncthreads();

    const float* prb = problems + (size_t)b * SLEN * 4;

    // ---------------- encoder (+ refp rows) ----------------
    for (int t = 0; t < SLEN; ++t) {
        // P1: gate partials over k-half
        {
            double a0 = 0., a1 = 0., a2 = 0., a3 = 0.;
#pragma unroll 8
            for (int kk = 0; kk < 128; ++kk) {
                double hk = h_s[kbase + kk];
                float4 w = WhE[((kbase + kk) << 8) + j];
                a0 += hk * (double)w.x; a1 += hk * (double)w.y;
                a2 += hk * (double)w.z; a3 += hk * (double)w.w;
            }
            pG[kh][j][0] = a0; pG[kh][j][1] = a1; pG[kh][j][2] = a2; pG[kh][j][3] = a3;
        }
        __syncthreads();
        // P2: finalize gates, update c,h (kh==0 threads)
        if (kh == 0) {
            float4 p = *(const float4*)(prb + (t << 2));
            float4 v = vE[j];
            float4 m0 = ME[j], m1 = ME[256 + j], m2 = ME[512 + j], m3 = ME[768 + j];
            double g0 = pG[0][j][0] + pG[1][j][0] + (double)v.x + (double)p.x * m0.x + (double)p.y * m1.x + (double)p.z * m2.x + (double)p.w * m3.x;
            double g1 = pG[0][j][1] + pG[1][j][1] + (double)v.y + (double)p.x * m0.y + (double)p.y * m1.y + (double)p.z * m2.y + (double)p.w * m3.y;
            double g2 = pG[0][j][2] + pG[1][j][2] + (double)v.z + (double)p.x * m0.z + (double)p.y * m1.z + (double)p.z * m2.z + (double)p.w * m3.z;
            double g3 = pG[0][j][3] + pG[1][j][3] + (double)v.w + (double)p.x * m0.w + (double)p.y * m1.w + (double)p.z * m2.w + (double)p.w * m3.w;
            float ig = sigf((float)g0), fg = sigf((float)g1), gg = tanhf((float)g2), og = sigf((float)g3);
            double c = (double)fg * c_s[j] + (double)ig * (double)gg;
            c_s[j] = c;
            h_s[j] = (double)og * (double)tanhf((float)c);
        }
        __syncthreads();
        // P3: Wr partials over NEW h
        {
            double rg = 0., rp_ = 0.;
#pragma unroll 8
            for (int kk = 0; kk < 128; ++kk) {
                double hk = h_s[kbase + kk];
                float2 wr = Wrgp[((kbase + kk) << 8) + j];
                rg += hk * (double)wr.x; rp_ += hk * (double)wr.y;
            }
            pG[kh][j][0] = rg; pG[kh][j][1] = rp_;
        }
        __syncthreads();
        // P4: write refp rows (kh halves split the two tables)
        if (kh == 0) refg[t * HDIM + j] = (float)(pG[0][j][0] + pG[1][j][0] + (double)br_g[j]);
        else         refp[t * HDIM + j] = (float)(pG[0][j][1] + pG[1][j][1] + (double)br_p[j]);
        __syncthreads();
    }

    // ---------------- decoder ----------------
    for (int t = 0; t < SLEN; ++t) {
        // P1: LSTM gate partials
        {
            double a0 = 0., a1 = 0., a2 = 0., a3 = 0.;
#pragma unroll 8
            for (int kk = 0; kk < 128; ++kk) {
                double hk = h_s[kbase + kk];
                float4 w = WhD[((kbase + kk) << 8) + j];
                a0 += hk * (double)w.x; a1 += hk * (double)w.y;
                a2 += hk * (double)w.z; a3 += hk * (double)w.w;
            }
            pG[kh][j][0] = a0; pG[kh][j][1] = a1; pG[kh][j][2] = a2; pG[kh][j][3] = a3;
        }
        __syncthreads();
        // P2: finalize
        if (kh == 0) {
            double g0, g1, g2, g3;
            if (t == 0) {
                float4 v = X0[j];
                g0 = pG[0][j][0] + pG[1][j][0] + (double)v.x;
                g1 = pG[0][j][1] + pG[1][j][1] + (double)v.y;
                g2 = pG[0][j][2] + pG[1][j][2] + (double)v.z;
                g3 = pG[0][j][3] + pG[1][j][3] + (double)v.w;
            } else {
                int a = lastA;
                float4 p = *(const float4*)(prb + (a << 2));
                float4 v = vD[j];
                float4 m0 = MD[j], m1 = MD[256 + j], m2 = MD[512 + j], m3 = MD[768 + j];
                g0 = pG[0][j][0] + pG[1][j][0] + (double)v.x + (double)p.x * m0.x + (double)p.y * m1.x + (double)p.z * m2.x + (double)p.w * m3.x;
                g1 = pG[0][j][1] + pG[1][j][1] + (double)v.y + (double)p.x * m0.y + (double)p.y * m1.y + (double)p.z * m2.y + (double)p.w * m3.y;
                g2 = pG[0][j][2] + pG[1][j][2] + (double)v.z + (double)p.x * m0.z + (double)p.y * m1.z + (double)p.z * m2.z + (double)p.w * m3.z;
                g3 = pG[0][j][3] + pG[1][j][3] + (double)v.w + (double)p.x * m0.w + (double)p.y * m1.w + (double)p.z * m2.w + (double)p.w * m3.w;
            }
            float ig = sigf((float)g0), fg = sigf((float)g1), gg = tanhf((float)g2), og = sigf((float)g3);
            double c = (double)fg * c_s[j] + (double)ig * (double)gg;
            c_s[j] = c;
            h_s[j] = (double)og * (double)tanhf((float)c);
        }
        __syncthreads();
        // P3: qp_g partials (f32)
        {
            float qa = 0.f;
#pragma unroll 8
            for (int kk = 0; kk < 128; ++kk)
                qa = fmaf((float)h_s[kbase + kk], WqgT[((kbase + kk) << 8) + j], qa);
            pA[kh][j] = qa;
        }
        __syncthreads();
        // P4: glimpse u — all 8 waves
        {
            const int d0 = lane, d1 = lane + 64, d2 = lane + 128, d3 = lane + 192;
            const float q0 = pA[0][d0] + pA[1][d0] + bq_g[d0], vg0 = V_g[d0];
            const float q1 = pA[0][d1] + pA[1][d1] + bq_g[d1], vg1 = V_g[d1];
            const float q2 = pA[0][d2] + pA[1][d2] + bq_g[d2], vg2 = V_g[d2];
            const float q3 = pA[0][d3] + pA[1][d3] + bq_g[d3], vg3 = V_g[d3];
            for (int s = wave; s < SLEN; s += 8) {
                if (vis[s]) continue;
                const float* r0 = refg + s * HDIM;
                float part;
                part = tanhf(q0 + r0[d0]) * 10.f * vg0;
                part = fmaf(tanhf(q1 + r0[d1]) * 10.f, vg1, part);
                part = fmaf(tanhf(q2 + r0[d2]) * 10.f, vg2, part);
                part = fmaf(tanhf(q3 + r0[d3]) * 10.f, vg3, part);
                for (int off = 32; off; off >>= 1) part += __shfl_xor(part, off, 64);
                if (lane == 0) u_l[s] = part;
            }
        }
        __syncthreads();
        // P5: glimpse softmax (wave 0)
        if (wave == 0) {
            int s1 = lane, s2 = lane + 64;
            bool v1 = vis[s1], v2 = vis[s2];
            float m = fmaxf(v1 ? -1e30f : u_l[s1], v2 ? -1e30f : u_l[s2]);
            for (int off = 32; off; off >>= 1) m = fmaxf(m, __shfl_xor(m, off, 64));
            float e1 = v1 ? 0.f : expf(u_l[s1] - m);
            float e2 = v2 ? 0.f : expf(u_l[s2] - m);
            float den = e1 + e2;
            for (int off = 32; off; off >>= 1) den += __shfl_xor(den, off, 64);
            w_l[s1] = e1 / den;
            w_l[s2] = e2 / den;
        }
        __syncthreads();
        // P6: q partials over s-half
        {
            float q = 0.f;
            int s0 = kh << 6;
            for (int s = s0; s < s0 + 64; ++s)
                if (!vis[s]) q = fmaf(w_l[s], refg[s * HDIM + j], q);
            pQ[kh][j] = q;
        }
        __syncthreads();
        // P7: qp_p partials
        {
            float qa = 0.f;
#pragma unroll 8
            for (int kk = 0; kk < 128; ++kk) {
                int k = kbase + kk;
                float qk = pQ[0][k] + pQ[1][k];
                qa = fmaf(qk, WqpT[(k << 8) + j], qa);
            }
            pP[kh][j] = qa;
        }
        __syncthreads();
        // P8: pointer logits — all 8 waves
        {
            const int d0 = lane, d1 = lane + 64, d2 = lane + 128, d3 = lane + 192;
            const float q0 = pP[0][d0] + pP[1][d0] + bq_p[d0], vp0 = V_p[d0];
            const float q1 = pP[0][d1] + pP[1][d1] + bq_p[d1], vp1 = V_p[d1];
            const float q2 = pP[0][d2] + pP[1][d2] + bq_p[d2], vp2 = V_p[d2];
            const float q3 = pP[0][d3] + pP[1][d3] + bq_p[d3], vp3 = V_p[d3];
            for (int s = wave; s < SLEN; s += 8) {
                if (vis[s]) continue;
                const float* r0 = refp + s * HDIM;
                float part;
                part = tanhf(q0 + r0[d0]) * 10.f * vp0;
                part = fmaf(tanhf(q1 + r0[d1]) * 10.f, vp1, part);
                part = fmaf(tanhf(q2 + r0[d2]) * 10.f, vp2, part);
                part = fmaf(tanhf(q3 + r0[d3]) * 10.f, vp3, part);
                for (int off = 32; off; off >>= 1) part += __shfl_xor(part, off, 64);
                if (lane == 0) u_l[s] = part;
            }
        }
        __syncthreads();
        // P9: sample (gumbel argmax, jax-exact) — wave 0
        if (wave == 0) {
            int s1 = lane, s2 = lane + 64;
            bool v1 = vis[s1], v2 = vis[s2];
            float m = fmaxf(v1 ? -1e30f : u_l[s1], v2 ? -1e30f : u_l[s2]);
            for (int off = 32; off; off >>= 1) m = fmaxf(m, __shfl_xor(m, off, 64));
            float e1 = v1 ? 0.f : expf(u_l[s1] - m);
            float e2 = v2 ? 0.f : expf(u_l[s2] - m);
            float den = e1 + e2;
            for (int off = 32; off; off >>= 1) den += __shfl_xor(den, off, 64);
            uint32_t kk0, kk1;
            tf2x32(0u, 1u, 0u, (uint32_t)t, kk0, kk1);
            double z1 = v1 ? -1.0e300 : (double)u_l[s1] + gumbel_jax(kk0, kk1, (uint32_t)(b * 128 + s1));
            double z2 = v2 ? -1.0e300 : (double)u_l[s2] + gumbel_jax(kk0, kk1, (uint32_t)(b * 128 + s2));
            double bz; int bi;
            if (z2 > z1) { bz = z2; bi = s2; } else { bz = z1; bi = s1; }
            for (int off = 32; off; off >>= 1) {
                double oz = __shfl_xor(bz, off, 64);
                int oi = __shfl_xor(bi, off, 64);
                if (oz > bz || (oz == bz && oi < bi)) { bz = oz; bi = oi; }
            }
            if (lane == 0) {
                float pr = expf(u_l[bi] - m) / den;
                out[t * NBATCH + b] = pr;
                out[SLEN * NBATCH + t * NBATCH + b] = (float)bi;
                vis[bi] = 1;
                lastA = bi;
            }
        }
        __syncthreads();
    }
}

extern "C" void kernel_launch(void* const* d_in, const int* in_sizes, int n_in,
                              void* d_out, int out_size, void* d_ws, size_t ws_size,
                              hipStream_t stream) {
    (void)d_ws; (void)ws_size; (void)n_in; (void)in_sizes; (void)out_size;
    const float* problems = (const float*)d_in[0];
    const float* embed_W  = (const float*)d_in[1];
    const float* embed_b  = (const float*)d_in[2];
    const float* Wi_enc   = (const float*)d_in[3];
    const float* Wh_enc   = (const float*)d_in[4];
    const float* b_enc    = (const float*)d_in[5];
    const float* Wi_dec   = (const float*)d_in[6];
    const float* Wh_dec   = (const float*)d_in[7];
    const float* b_dec    = (const float*)d_in[8];
    const float* dec0     = (const float*)d_in[9];
    const float* Wq_g     = (const float*)d_in[10];
    const float* bq_g     = (const float*)d_in[11];
    const float* Wr_g     = (const float*)d_in[12];
    const float* br_g     = (const float*)d_in[13];
    const float* V_g      = (const float*)d_in[14];
    const float* Wq_p     = (const float*)d_in[15];
    const float* bq_p     = (const float*)d_in[16];
    const float* Wr_p     = (const float*)d_in[17];
    const float* br_p     = (const float*)d_in[18];
    const float* V_p      = (const float*)d_in[19];
    float* outp = (float*)d_out;

    hipLaunchKernelGGL(pre_k, dim3(512), dim3(256), 0, stream,
                       embed_W, embed_b, Wi_enc, Wh_enc, b_enc,
                       Wi_dec, Wh_dec, b_dec, dec0, Wq_g, Wr_g, Wq_p, Wr_p);
    hipLaunchKernelGGL(main_k, dim3(512), dim3(512), 0, stream,
                       problems, bq_g, br_g, V_g, bq_p, br_p, V_p, outp);
}